// Round 6
// baseline (152.881 us; speedup 1.0000x reference)
//
#include <hip/hip_runtime.h>
#include <hip/hip_bf16.h>

#define BQ   16
#define BK2  32     // 2B
#define SEQ  256
#define HD   768
#define NKT  24     // HD / 32 K-tiles

typedef __attribute__((ext_vector_type(8))) short bf16x8;
typedef __attribute__((ext_vector_type(4))) float f32x4;

__device__ __forceinline__ void glds16(const unsigned short* g, unsigned short* l) {
    __builtin_amdgcn_global_load_lds(
        (const __attribute__((address_space(1))) unsigned int*)g,
        (__attribute__((address_space(3))) unsigned int*)l, 16, 0, 0);
}

// branch-free RNE fp32->bf16, packed two at a time
__device__ __forceinline__ unsigned int pack2_bf16(float a, float b) {
    unsigned ua = __float_as_uint(a), ub = __float_as_uint(b);
    ua += 0x7FFFu + ((ua >> 16) & 1u);
    ub += 0x7FFFu + ((ub >> 16) & 1u);
    return (ua >> 16) | (ub & 0xFFFF0000u);
}

// ---------------- Phase 1: fp32 l2-normalize -> bf16 ----------------------
__global__ __launch_bounds__(256) void norm_kernel(
    const float* __restrict__ q, const float* __restrict__ k,
    unsigned short* __restrict__ qn, unsigned short* __restrict__ kn)
{
    int row  = blockIdx.x * 4 + (threadIdx.x >> 6);
    int lane = threadIdx.x & 63;
    const int NQ = BQ * SEQ;
    const float* src = (row < NQ) ? q + (size_t)row * HD
                                  : k + (size_t)(row - NQ) * HD;
    unsigned int* dst = (unsigned int*)((row < NQ) ? qn + (size_t)row * HD
                                                   : kn + (size_t)(row - NQ) * HD);
    float4 v[3];
    float ss = 0.f;
#pragma unroll
    for (int c = 0; c < 3; ++c) {
        v[c] = ((const float4*)src)[lane + 64 * c];
        ss += v[c].x * v[c].x + v[c].y * v[c].y + v[c].z * v[c].z + v[c].w * v[c].w;
    }
#pragma unroll
    for (int m = 1; m < 64; m <<= 1) ss += __shfl_xor(ss, m, 64);
    float inv = rsqrtf(fmaxf(ss, 1e-24f));
#pragma unroll
    for (int c = 0; c < 3; ++c) {
        uint2 o = make_uint2(pack2_bf16(v[c].x * inv, v[c].y * inv),
                             pack2_bf16(v[c].z * inv, v[c].w * inv));
        ((uint2*)dst)[lane + 64 * c] = o;
    }
}

// ---------------- Phase 2: block = (j, i) covering FULL 256 s x 256 t -----
// m201-template fine-phase port: BK=32, TRIPLE-buffered LDS (96 KB), 8 waves
// 2(s)x4(t), per-wave 128x64 (acc[8][4]). Per K-tile: 2 phases of 16 MFMA,
// each phase = {ds_read frags -> issue 2 glds (tile kt+2) -> s_barrier ->
// lgkmcnt(0) -> setprio(1) 16xMFMA setprio(0)}. Reads issued BEFORE the
// barrier hide under barrier skew (m196's fine-interleave lever).
// Counted vmcnt(4) steady state (stage lead = 2 tiles), drains only at tail.
// Chunk swizzle = round-4's measured-0-conflict pair.
__global__ __launch_bounds__(512, 2) void li_kernel(
    const unsigned short* __restrict__ qn, const unsigned short* __restrict__ kn,
    const float* __restrict__ g_ls, const float* __restrict__ g_ar,
    const int* __restrict__ q_mask, const int* __restrict__ k_mask,
    float* __restrict__ out)
{
    // XCD-aware bijective remap: xcd = bid&7 owns an 8x8 (i,j) sub-rectangle.
    const int bid   = blockIdx.x;
    const int xcd   = bid & 7, local = bid >> 3;        // local 0..63
    const int i = (xcd & 1) * 8 + (local >> 3);         // 0..15
    const int j = (xcd >> 1) * 8 + (local & 7);         // 0..31

    const int tid  = threadIdx.x;
    const int w    = tid >> 6, lane = tid & 63;
    const int ln   = lane & 15, lg = lane >> 4;
    const int wsd  = w >> 2, wt = w & 3;     // wave = (s-half, t-quarter)

    __shared__ __align__(16) unsigned short As[3 * 256 * 32];  // 48 KB, 3-buf
    __shared__ __align__(16) unsigned short Bs[3 * 256 * 32];  // 48 KB, 3-buf
    __shared__ float w2[SEQ];      // scale * exp(-alpha*d)
    __shared__ float kmB[SEQ];
    __shared__ float red[8];

    float a0 = g_ar[0];
    float alpha = (a0 > 0.f) ? a0 : 0.01f * a0;        // leaky_relu
    float scale = __expf(g_ls[0]);
    if (tid < 256) w2[tid] = scale * __expf(-alpha * (float)tid);
    else           kmB[tid - 256] = (k_mask[j * SEQ + (tid - 256)] != 0) ? 1.f : 0.f;

    // staging (r4-verified swizzle, 0 conflicts): wave w owns rows
    // [w*32, w*32+32) of A and B per K-tile (2 glds each, 16 rows per glds).
    // lane l: row srow = l>>2, LDS slot (l&3), source chunk (l&3)^((srow>>1)&3).
    const int srow = lane >> 2;                       // 0..15 in 16-row group
    const int gch  = (lane & 3) ^ ((srow >> 1) & 3);
    const unsigned short* aq = qn + ((size_t)i * SEQ + w * 32 + srow) * HD + gch * 8;
    const unsigned short* bq = kn + ((size_t)j * SEQ + w * 32 + srow) * HD + gch * 8;

    f32x4 acc[8][4];
    const f32x4 zero4 = {0.f, 0.f, 0.f, 0.f};
#pragma unroll
    for (int a = 0; a < 8; ++a)
#pragma unroll
        for (int b = 0; b < 4; ++b) acc[a][b] = zero4;

    const int rsw = (ln >> 1) & 3;    // read-side chunk XOR (row ≡ ln mod 16)

    __syncthreads();                  // w2/kmB ordering + wave alignment

    // prologue: tile 0 -> buf0, tile 1 -> buf1 (8 glds in flight per wave)
#define PSTAGE(kt, B) do {                                            \
        const int kk_ = (kt) * 32;                                    \
        glds16(aq + kk_,           As + (B) * 8192 + w * 1024);       \
        glds16(bq + kk_,           Bs + (B) * 8192 + w * 1024);       \
        glds16(aq + kk_ + 16 * HD, As + (B) * 8192 + w * 1024 + 512); \
        glds16(bq + kk_ + 16 * HD, Bs + (B) * 8192 + w * 1024 + 512); \
    } while (0)
    PSTAGE(0, 0);
    PSTAGE(1, 1);
#undef PSTAGE

    // one K-tile = 2 fine phases; CB = buf of tile kt, SB = buf of tile kt+2
#define TILE(kt, CB, SB) do {                                                  \
    if ((kt) == NKT - 1) asm volatile("s_waitcnt vmcnt(0)" ::: "memory");      \
    else                 asm volatile("s_waitcnt vmcnt(4)" ::: "memory");      \
    __builtin_amdgcn_sched_barrier(0);                                         \
    __builtin_amdgcn_s_barrier();      /* tile-kt LDS visible; kt-1 reads done */ \
    {                                                                          \
    const bf16x8* A8 = (const bf16x8*)(As + (CB) * 8192);                      \
    const bf16x8* B8 = (const bf16x8*)(Bs + (CB) * 8192);                      \
    const int skk = ((kt) + 2) * 32;                                           \
    const bool dostage = ((kt) + 2 < NKT);                                     \
    unsigned short* Ad = As + (SB) * 8192 + w * 1024;                          \
    unsigned short* Bd = Bs + (SB) * 8192 + w * 1024;                          \
    bf16x8 af[4], bfr[4];                                                      \
    /* ---- phase 0: rows 0..63 of wave tile ---- */                           \
    _Pragma("unroll")                                                          \
    for (int cn = 0; cn < 4; ++cn)                                             \
        bfr[cn] = B8[(wt * 64 + cn * 16 + ln) * 4 + (lg ^ rsw)];               \
    _Pragma("unroll")                                                          \
    for (int rm = 0; rm < 4; ++rm)                                             \
        af[rm] = A8[(wsd * 128 + rm * 16 + ln) * 4 + (lg ^ rsw)];              \
    if (dostage) { glds16(aq + skk, Ad); glds16(bq + skk, Bd); }               \
    __builtin_amdgcn_s_barrier();                                              \
    asm volatile("s_waitcnt lgkmcnt(0)" ::: "memory");                         \
    __builtin_amdgcn_sched_barrier(0);                                         \
    __builtin_amdgcn_s_setprio(1);                                             \
    _Pragma("unroll")                                                          \
    for (int rm = 0; rm < 4; ++rm)                                             \
        _Pragma("unroll")                                                      \
        for (int cn = 0; cn < 4; ++cn)                                         \
            acc[rm][cn] = __builtin_amdgcn_mfma_f32_16x16x32_bf16(             \
                af[rm], bfr[cn], acc[rm][cn], 0, 0, 0);                        \
    __builtin_amdgcn_s_setprio(0);                                             \
    /* ---- phase 1: rows 64..127 of wave tile ---- */                         \
    _Pragma("unroll")                                                          \
    for (int rm = 0; rm < 4; ++rm)                                             \
        af[rm] = A8[(wsd * 128 + (rm + 4) * 16 + ln) * 4 + (lg ^ rsw)];        \
    if (dostage) { glds16(aq + skk + 16 * HD, Ad + 512);                       \
                   glds16(bq + skk + 16 * HD, Bd + 512); }                     \
    __builtin_amdgcn_s_barrier();                                              \
    asm volatile("s_waitcnt lgkmcnt(0)" ::: "memory");                         \
    __builtin_amdgcn_sched_barrier(0);                                         \
    __builtin_amdgcn_s_setprio(1);                                             \
    _Pragma("unroll")                                                          \
    for (int rm = 0; rm < 4; ++rm)                                             \
        _Pragma("unroll")                                                      \
        for (int cn = 0; cn < 4; ++cn)                                         \
            acc[rm + 4][cn] = __builtin_amdgcn_mfma_f32_16x16x32_bf16(         \
                af[rm], bfr[cn], acc[rm + 4][cn], 0, 0, 0);                    \
    __builtin_amdgcn_s_setprio(0);                                             \
    }                                                                          \
} while (0)

#pragma unroll 1
    for (int kt = 0; kt < NKT; kt += 3) {   // tile T uses buf T%3; stages T+2
        TILE(kt,     0, 2);
        TILE(kt + 1, 1, 0);
        TILE(kt + 2, 2, 1);
    }
#undef TILE

    // epilogue: C/D layout col=ln (t), row=lg*4+r (s)   [verified r2/r3/r5]
    __syncthreads();                    // full drain; reuse As as scratch
    float* zs  = (float*)As;            // [256][4] Z partials per (s, wt)
    float* wsc = zs + 1024;             // [256][4] W partials

#pragma unroll
    for (int rm = 0; rm < 8; ++rm)
#pragma unroll
        for (int r = 0; r < 4; ++r) {
            int s = wsd * 128 + rm * 16 + lg * 4 + r;     // global s (full 256)
            float ze = 0.f, we = 0.f;
#pragma unroll
            for (int cn = 0; cn < 4; ++cn) {
                int t = wt * 64 + cn * 16 + ln;           // global t (full 256)
                float sim = acc[rm][cn][r];
                int d = s - t; d = (d < 0) ? -d : d;
                float e = kmB[t] * __expf(sim * w2[d]);
                ze += e;
                we = fmaf(e, sim, we);
            }
#pragma unroll
            for (int m = 1; m < 16; m <<= 1) {            // reduce over t-16 lanes
                ze += __shfl_xor(ze, m, 64);
                we += __shfl_xor(we, m, 64);
            }
            if (ln == 0) { zs[s * 4 + wt] = ze; wsc[s * 4 + wt] = we; }
        }
    __syncthreads();

    float part = 0.f;
    if (tid < 256) {
        const float4 Z4 = ((const float4*)zs)[tid];
        const float4 W4 = ((const float4*)wsc)[tid];
        float Z = Z4.x + Z4.y + Z4.z + Z4.w;
        float W = W4.x + W4.y + W4.z + W4.w;
        float pt = (Z > 0.f) ? (W / Z) : 0.f;
        part = pt * (float)q_mask[i * SEQ + tid];
    }
#pragma unroll
    for (int m = 1; m < 64; m <<= 1) part += __shfl_xor(part, m, 64);
    if (lane == 0) red[w] = part;
    __syncthreads();
    if (tid == 0) {
        float tot = red[0] + red[1] + red[2] + red[3]
                  + red[4] + red[5] + red[6] + red[7];
        out[i * BK2 + j] = tot;     // exactly one block per output element
    }
}

extern "C" void kernel_launch(void* const* d_in, const int* in_sizes, int n_in,
                              void* d_out, int out_size, void* d_ws, size_t ws_size,
                              hipStream_t stream) {
    const float* q  = (const float*)d_in[0];   // [16,256,768] f32
    const float* k  = (const float*)d_in[1];   // [32,256,768] f32
    const float* ls = (const float*)d_in[2];   // scalar
    const float* ar = (const float*)d_in[3];   // scalar
    const int* qm   = (const int*)d_in[4];     // [16,256]
    const int* km   = (const int*)d_in[5];     // [32,256]
    float* out      = (float*)d_out;           // [16,32] f32

    unsigned short* qn = (unsigned short*)d_ws;            // 16*256*768 bf16
    unsigned short* kn = qn + (size_t)BQ * SEQ * HD;       // 32*256*768 bf16

    norm_kernel<<<(BQ + BK2) * SEQ / 4, 256, 0, stream>>>(q, k, qn, kn);
    li_kernel<<<BK2 * BQ, 512, 0, stream>>>(qn, kn, ls, ar, qm, km, (float*)d_out);
}

// Round 7
// 137.912 us; speedup vs baseline: 1.1085x; 1.1085x over previous
//
#include <hip/hip_runtime.h>
#include <hip/hip_bf16.h>

#define BQ   16
#define BK2  32     // 2B
#define SEQ  256
#define HD   768

typedef __attribute__((ext_vector_type(8))) short bf16x8;
typedef __attribute__((ext_vector_type(4))) float f32x4;

__device__ __forceinline__ void glds16(const unsigned short* g, unsigned short* l) {
    __builtin_amdgcn_global_load_lds(
        (const __attribute__((address_space(1))) unsigned int*)g,
        (__attribute__((address_space(3))) unsigned int*)l, 16, 0, 0);
}

// branch-free RNE fp32->bf16, packed two at a time
__device__ __forceinline__ unsigned int pack2_bf16(float a, float b) {
    unsigned ua = __float_as_uint(a), ub = __float_as_uint(b);
    ua += 0x7FFFu + ((ua >> 16) & 1u);
    ub += 0x7FFFu + ((ub >> 16) & 1u);
    return (ua >> 16) | (ub & 0xFFFF0000u);
}

// ---------------- Phase 1: fp32 l2-normalize -> bf16 (+ zero d_out) --------
__global__ __launch_bounds__(256) void norm_kernel(
    const float* __restrict__ q, const float* __restrict__ k,
    unsigned short* __restrict__ qn, unsigned short* __restrict__ kn,
    float* __restrict__ out)
{
    if (blockIdx.x == 0 && threadIdx.x < 256) {      // zero 512-elem out for li's atomics
        out[threadIdx.x] = 0.f; out[threadIdx.x + 256] = 0.f;
    }
    int row  = blockIdx.x * 4 + (threadIdx.x >> 6);
    int lane = threadIdx.x & 63;
    const int NQ = BQ * SEQ;
    const float* src = (row < NQ) ? q + (size_t)row * HD
                                  : k + (size_t)(row - NQ) * HD;
    unsigned int* dst = (unsigned int*)((row < NQ) ? qn + (size_t)row * HD
                                                   : kn + (size_t)(row - NQ) * HD);
    float4 v[3];
    float ss = 0.f;
#pragma unroll
    for (int c = 0; c < 3; ++c) {
        v[c] = ((const float4*)src)[lane + 64 * c];
        ss += v[c].x * v[c].x + v[c].y * v[c].y + v[c].z * v[c].z + v[c].w * v[c].w;
    }
#pragma unroll
    for (int m = 1; m < 64; m <<= 1) ss += __shfl_xor(ss, m, 64);
    float inv = rsqrtf(fmaxf(ss, 1e-24f));
#pragma unroll
    for (int c = 0; c < 3; ++c) {
        uint2 o = make_uint2(pack2_bf16(v[c].x * inv, v[c].y * inv),
                             pack2_bf16(v[c].z * inv, v[c].w * inv));
        ((uint2*)dst)[lane + 64 * c] = o;
    }
}

// ---------------- Phase 2: block = (j, i, sh) covering 128 s x 256 t (full t)
// ROUND-0 K-loop verbatim (measured best: 63.4 us, 2 blocks/CU, 0 conflicts).
// Epilogue slimmed: 2-step shfl + [16][132] scratch in Bs (conflict-free both
// sides), kmB hoisted to regs, w2 pre-scaled by log2(e) + exp2f.
__global__ __launch_bounds__(512, 2) void li_kernel(
    const unsigned short* __restrict__ qn, const unsigned short* __restrict__ kn,
    const float* __restrict__ g_ls, const float* __restrict__ g_ar,
    const int* __restrict__ q_mask, const int* __restrict__ k_mask,
    float* __restrict__ out)
{
    const int j  = blockIdx.x, i = blockIdx.y, sh = blockIdx.z;
    const int tid  = threadIdx.x;
    const int w    = tid >> 6, lane = tid & 63;
    const int ln   = lane & 15, lg = lane >> 4;
    const int wsd  = w >> 2, wt = w & 3;     // wave = (s-half, t-quarter)

    __shared__ __align__(16) unsigned short As[128 * 64];  // 16 KB, swizzled
    __shared__ __align__(16) unsigned short Bs[256 * 64];  // 32 KB, swizzled
    __shared__ float w2[SEQ];      // scale * exp(-alpha*d) * log2(e)
    __shared__ float kmB[SEQ];
    __shared__ float red[8];

    float a0 = g_ar[0];
    float alpha = (a0 > 0.f) ? a0 : 0.01f * a0;        // leaky_relu
    float scale = __expf(g_ls[0]) * 1.4426950408889634f;   // fold log2(e): use exp2
    if (tid < 256) w2[tid] = scale * __expf(-alpha * (float)tid);
    else           kmB[tid - 256] = (k_mask[j * SEQ + (tid - 256)] != 0) ? 1.f : 0.f;

    // glds staging: lane covers row (base + lane>>3), swizzled source chunk
    const int rl  = lane >> 3;
    const int gch = (lane & 7) ^ rl;      // LDS chunk slot (lane&7) <- global chunk (lane&7)^row&7
    const unsigned short* aq = qn + ((size_t)i * SEQ + sh * 128 + w * 8 + rl) * HD + gch * 8;
    const unsigned short* bq = kn + ((size_t)j * SEQ + w * 8 + rl) * HD + gch * 8;
    unsigned short* al = As + (w * 8) * 64;
    unsigned short* bl = Bs + (w * 8) * 64;

    f32x4 acc[4][4];
    const f32x4 zero4 = {0.f, 0.f, 0.f, 0.f};
#pragma unroll
    for (int a = 0; a < 4; ++a)
#pragma unroll
        for (int b = 0; b < 4; ++b) acc[a][b] = zero4;

    for (int kk = 0; kk < HD; kk += 64) {
        __syncthreads();                       // prev stage consumed
        glds16(aq + kk,           al);                 // A rows 0..63 (w*8+rl)
        glds16(aq + kk + 64 * HD, al + 64 * 64);       // A rows 64..127
#pragma unroll
        for (int c = 0; c < 4; ++c)                    // B rows 0..255
            glds16(bq + kk + c * (64 * HD), bl + c * (64 * 64));
        __syncthreads();                       // vmcnt drained before barrier
        const bf16x8* A8 = (const bf16x8*)As;
        const bf16x8* B8 = (const bf16x8*)Bs;
#pragma unroll
        for (int ks = 0; ks < 2; ++ks) {
            const int ch = (ks * 4 + lg) ^ (ln & 7);   // unswizzle
            bf16x8 af[4], bfr[4];
#pragma unroll
            for (int rm = 0; rm < 4; ++rm)
                af[rm] = A8[(wsd * 64 + rm * 16 + ln) * 8 + ch];
#pragma unroll
            for (int cn = 0; cn < 4; ++cn)
                bfr[cn] = B8[(wt * 64 + cn * 16 + ln) * 8 + ch];
#pragma unroll
            for (int rm = 0; rm < 4; ++rm)
#pragma unroll
                for (int cn = 0; cn < 4; ++cn)
                    acc[rm][cn] = __builtin_amdgcn_mfma_f32_16x16x32_bf16(
                        af[rm], bfr[cn], acc[rm][cn], 0, 0, 0);
        }
    }

    // ---------------- slim epilogue ----------------
    // C/D layout col=ln (t), row=lg*4+r (s).
    // kmB hoisted; 2-step shfl (16->4 lanes); partials to Bs scratch
    // [16][132] f32 (write: stride-132 spreads (ln>>2) across banks;
    // read: lane-stride-1, conflict-free).
    __syncthreads();                    // all As/Bs MFMA reads done
    float* zs  = (float*)Bs;            // [16][132] Z partials
    float* wsc = zs + 16 * 132;         // [16][132] W partials

    float km[4];
#pragma unroll
    for (int cn = 0; cn < 4; ++cn) km[cn] = kmB[wt * 64 + cn * 16 + ln];

#pragma unroll
    for (int rm = 0; rm < 4; ++rm)
#pragma unroll
        for (int r = 0; r < 4; ++r) {
            int srow = wsd * 64 + rm * 16 + lg * 4 + r;   // s within block's 128
            int s  = sh * 128 + srow;
            float ze = 0.f, we = 0.f;
#pragma unroll
            for (int cn = 0; cn < 4; ++cn) {
                int t = wt * 64 + cn * 16 + ln;           // global t (full 256 in-block)
                float sim = acc[rm][cn][r];
                int d = s - t; d = (d < 0) ? -d : d;
                float e = km[cn] * __builtin_exp2f(sim * w2[d]);
                ze += e;
                we = fmaf(e, sim, we);
            }
            ze += __shfl_xor(ze, 1, 64);  we += __shfl_xor(we, 1, 64);
            ze += __shfl_xor(ze, 2, 64);  we += __shfl_xor(we, 2, 64);
            if ((ln & 3) == 0) {
                int zrow = wt * 4 + (ln >> 2);            // 0..15
                zs [zrow * 132 + srow] = ze;
                wsc[zrow * 132 + srow] = we;
            }
        }
    __syncthreads();

    float part = 0.f;
    if (tid < 128) {
        float Z = 0.f, W = 0.f;
#pragma unroll
        for (int c = 0; c < 16; ++c) {
            Z += zs [c * 132 + tid];
            W += wsc[c * 132 + tid];
        }
        float pt = (Z > 0.f) ? (W / Z) : 0.f;
        part = pt * (float)q_mask[i * SEQ + sh * 128 + tid];
    }
#pragma unroll
    for (int m = 1; m < 64; m <<= 1) part += __shfl_xor(part, m, 64);
    if (lane == 0) red[w] = part;
    __syncthreads();
    if (tid == 0) {
        float tot = red[0] + red[1] + red[2] + red[3]
                  + red[4] + red[5] + red[6] + red[7];
        atomicAdd(&out[i * BK2 + j], tot);
    }
}

extern "C" void kernel_launch(void* const* d_in, const int* in_sizes, int n_in,
                              void* d_out, int out_size, void* d_ws, size_t ws_size,
                              hipStream_t stream) {
    const float* q  = (const float*)d_in[0];   // [16,256,768] f32
    const float* k  = (const float*)d_in[1];   // [32,256,768] f32
    const float* ls = (const float*)d_in[2];   // scalar
    const float* ar = (const float*)d_in[3];   // scalar
    const int* qm   = (const int*)d_in[4];     // [16,256]
    const int* km   = (const int*)d_in[5];     // [32,256]
    float* out      = (float*)d_out;           // [16,32] f32

    unsigned short* qn = (unsigned short*)d_ws;            // 16*256*768 bf16
    unsigned short* kn = qn + (size_t)BQ * SEQ * HD;       // 32*256*768 bf16

    norm_kernel<<<(BQ + BK2) * SEQ / 4, 256, 0, stream>>>(q, k, qn, kn, (float*)d_out);
    li_kernel<<<dim3(BK2, BQ, 2), 512, 0, stream>>>(qn, kn, ls, ar, qm, km, (float*)d_out);
}